// Round 9
// baseline (230.798 us; speedup 1.0000x reference)
//
#include <hip/hip_runtime.h>
#include <hip/hip_cooperative_groups.h>
#include <math.h>

namespace cg = cooperative_groups;

#define LL 1024
#define DD 512
#define HH 256

// ws layout (floats):
//   pC  : [4][512][1024] @ 0        gemm K-partials (n = mat*256+h)  (8 MB)
//   sraw: [1024][1024]   @ 2097152  P(i,j) = A_i + B_j + sum|t+u|w   (4 MB)

// LDS arena (floats), reused across phases:
//   phase1: Sl[2][128][36] @ 0 (9216), Wl[2][64][36] @ 9216 (4608)
//   phase2: Tl[256][72] @ 0, Ul[256][72] @ 18432, PA[4][128] @ 36864,
//           As[64] @ 37376, Bs[64] @ 37440   (total 37504)
//   phase3: B[64][65] @ 0 (4160)
#define ARENA_F 37504

__global__ __launch_bounds__(512) void sp_mega(
    const float* __restrict__ S, const float* __restrict__ W1,
    const float* __restrict__ b1, const float* __restrict__ W2,
    const float* __restrict__ b2, float* __restrict__ ws,
    float* __restrict__ out) {
  __shared__ float arena[ARENA_F];   // 150 KB -> 1 block/CU, 512 thr = 2 w/SIMD
  cg::grid_group grid = cg::this_grid();

  const int tid = threadIdx.x;
  const int bid = blockIdx.x;
  float* pC   = ws;                          // [4][512][1024]
  float* sraw = ws + 4 * 512 * LL;           // [1024][1024]

  // ===== Phase 1: GEMM partials (R7-proven shape: 128i x 64n, 4x4/thr) =====
  {
    const int ib = bid & 7, nb = (bid >> 3) & 7, z = bid >> 6;
    const int i0 = ib * 128, n0 = nb * 64, kz = z * 128;
    float* Sl = arena;            // [2][128][36]
    float* Wl = arena + 9216;     // [2][64][36]

    const int tx = tid & 15;      // n = n0 + tx + 16b
    const int ty = tid >> 4;      // i = i0 + 4ty + a, ty 0..31
    const int srow = tid >> 3;    // 0..63
    const int ssl  = tid & 7;
    const int wn   = n0 + srow;

    const float* s0 = S + (size_t)(i0 + srow) * DD + kz + 4 * ssl;
    const float* s1 = s0 + (size_t)64 * DD;
    const float* w0 = W1 + (size_t)(wn & 255) * (2 * DD) + (wn >> 8) * DD + kz + 4 * ssl;

    float4 sA, sB, wA;
    float acc[4][4] = {{0.f}};

    // chunk 0
    sA = *(const float4*)(s0);
    sB = *(const float4*)(s1);
    wA = *(const float4*)(w0);
    *(float4*)&Sl[srow * 36 + 4 * ssl]        = sA;
    *(float4*)&Sl[(64 + srow) * 36 + 4 * ssl] = sB;
    *(float4*)&Wl[srow * 36 + 4 * ssl]        = wA;
    __syncthreads();

    for (int c = 0; c < 4; ++c) {
      const int cur = c & 1;
      if (c < 3) {
        sA = *(const float4*)(s0 + 32 * (c + 1));
        sB = *(const float4*)(s1 + 32 * (c + 1));
        wA = *(const float4*)(w0 + 32 * (c + 1));
      }
      #pragma unroll 2
      for (int k4 = 0; k4 < 8; ++k4) {
        float4 wf[4], sf[4];
        #pragma unroll
        for (int b = 0; b < 4; ++b)
          wf[b] = *(const float4*)&Wl[cur * 2304 + (tx + 16 * b) * 36 + 4 * k4];
        #pragma unroll
        for (int a = 0; a < 4; ++a)
          sf[a] = *(const float4*)&Sl[cur * 4608 + (4 * ty + a) * 36 + 4 * k4];
        #pragma unroll
        for (int a = 0; a < 4; ++a) {
          #pragma unroll
          for (int b = 0; b < 4; ++b) {
            acc[a][b] += sf[a].x * wf[b].x + sf[a].y * wf[b].y +
                         sf[a].z * wf[b].z + sf[a].w * wf[b].w;
          }
        }
      }
      if (c < 3) {
        const int nb2 = cur ^ 1;
        *(float4*)&Sl[nb2 * 4608 + srow * 36 + 4 * ssl]        = sA;
        *(float4*)&Sl[nb2 * 4608 + (64 + srow) * 36 + 4 * ssl] = sB;
        *(float4*)&Wl[nb2 * 2304 + srow * 36 + 4 * ssl]        = wA;
      }
      __syncthreads();
    }

    float* base = pC + (size_t)z * (512 * LL);
    #pragma unroll
    for (int b = 0; b < 4; ++b) {
      const int n = n0 + tx + 16 * b;
      *(float4*)(base + (size_t)n * LL + i0 + 4 * ty) =
          make_float4(acc[0][b], acc[1][b], acc[2][b], acc[3][b]);
    }
  }

  __threadfence();
  grid.sync();

  // ===== Phase 2: pairwise. P = A_i + B_j + sum_h |t+u|*w2 (relu=(x+|x|)/2) =====
  {
    const int bj = bid & 15, bi = bid >> 4;
    const int j0 = bj * 64, i0 = bi * 64;
    float* Tl = arena;            // [256][72]
    float* Ul = arena + 18432;    // [256][72]
    float* PA = arena + 36864;    // [4][128]
    float* As = arena + 37376;    // [64]
    float* Bs = arena + 37440;    // [64]

    // stage panels, summing 4 K-partials; fold b1 into T
    #pragma unroll
    for (int q = 0; q < 8; ++q) {
      const int m = q * 512 + tid;            // 0..4095
      const int h = m >> 4;
      const int g4 = (m & 15) * 4;
      const float* pt = pC + (size_t)h * LL + i0 + g4;
      const float* pu = pC + (size_t)(HH + h) * LL + j0 + g4;
      float4 t0 = *(const float4*)(pt);
      float4 t1 = *(const float4*)(pt + 512 * LL);
      float4 t2 = *(const float4*)(pt + 2 * 512 * LL);
      float4 t3 = *(const float4*)(pt + 3 * 512 * LL);
      float4 u0 = *(const float4*)(pu);
      float4 u1 = *(const float4*)(pu + 512 * LL);
      float4 u2 = *(const float4*)(pu + 2 * 512 * LL);
      float4 u3 = *(const float4*)(pu + 3 * 512 * LL);
      const float bb = b1[h];
      *(float4*)&Tl[h * 72 + g4] =
          make_float4(t0.x + t1.x + t2.x + t3.x + bb,
                      t0.y + t1.y + t2.y + t3.y + bb,
                      t0.z + t1.z + t2.z + t3.z + bb,
                      t0.w + t1.w + t2.w + t3.w + bb);
      *(float4*)&Ul[h * 72 + g4] =
          make_float4(u0.x + u1.x + u2.x + u3.x,
                      u0.y + u1.y + u2.y + u3.y,
                      u0.z + u1.z + u2.z + u3.z,
                      u0.w + u1.w + u2.w + u3.w);
    }
    __syncthreads();

    // rank-1 prologue: 128 cols x 4 h-slices of 64
    {
      const int x = tid & 127, hs = tid >> 7;
      const float* pan = (x < 64) ? (Tl + x) : (Ul + (x - 64));
      float p = 0.f;
      #pragma unroll 8
      for (int n = 0; n < 64; ++n) {
        const int h = hs * 64 + n;
        p = fmaf(pan[h * 72], W2[h], p);
      }
      PA[hs * 128 + x] = p;
    }
    __syncthreads();
    if (tid < 128) {
      const float s_ = PA[tid] + PA[128 + tid] + PA[256 + tid] + PA[384 + tid];
      if (tid < 64) As[tid] = s_; else Bs[tid - 64] = s_;
    }
    __syncthreads();

    const int tx = tid & 15;      // j = j0 + 4tx + b
    const int ty = tid >> 4;      // i = i0 + 2ty + a, ty 0..31
    float a0[4] = {0.f, 0.f, 0.f, 0.f};
    float a1[4] = {0.f, 0.f, 0.f, 0.f};

    #pragma unroll 4
    for (int h = 0; h < HH; ++h) {
      const float2 tv = *(const float2*)&Tl[h * 72 + 2 * ty];
      const float4 uv = *(const float4*)&Ul[h * 72 + 4 * tx];
      const float w = W2[h];
      a0[0] = fmaf(fabsf(tv.x + uv.x), w, a0[0]);
      a0[1] = fmaf(fabsf(tv.x + uv.y), w, a0[1]);
      a0[2] = fmaf(fabsf(tv.x + uv.z), w, a0[2]);
      a0[3] = fmaf(fabsf(tv.x + uv.w), w, a0[3]);
      a1[0] = fmaf(fabsf(tv.y + uv.x), w, a1[0]);
      a1[1] = fmaf(fabsf(tv.y + uv.y), w, a1[1]);
      a1[2] = fmaf(fabsf(tv.y + uv.z), w, a1[2]);
      a1[3] = fmaf(fabsf(tv.y + uv.w), w, a1[3]);
    }

    const float A0 = As[2 * ty], A1 = As[2 * ty + 1];
    const float B0 = Bs[4 * tx], B1 = Bs[4 * tx + 1];
    const float B2 = Bs[4 * tx + 2], B3 = Bs[4 * tx + 3];
    float* p0 = sraw + (size_t)(i0 + 2 * ty) * LL + j0 + 4 * tx;
    *(float4*)p0 = make_float4(a0[0] + A0 + B0, a0[1] + A0 + B1,
                               a0[2] + A0 + B2, a0[3] + A0 + B3);
    *(float4*)(p0 + LL) = make_float4(a1[0] + A1 + B0, a1[1] + A1 + B1,
                                      a1[2] + A1 + B2, a1[3] + A1 + B3);
  }

  __threadfence();
  grid.sync();

  // ===== Phase 3: out = sigmoid(0.25*(P + P^T) + b2) =====
  {
    const int bj = bid & 15, bi = bid >> 4;
    const int i0 = bi * 64, j0 = bj * 64;
    float* B = arena;   // [64][65]

    #pragma unroll
    for (int a = 0; a < 2; ++a) {
      const int m = a * 512 + tid;
      const int row = m >> 4;
      const int g4 = (m & 15) * 4;
      const float4 v = *(const float4*)(sraw + (size_t)(j0 + row) * LL + i0 + g4);
      B[row * 65 + g4 + 0] = v.x;
      B[row * 65 + g4 + 1] = v.y;
      B[row * 65 + g4 + 2] = v.z;
      B[row * 65 + g4 + 3] = v.w;
    }
    __syncthreads();

    const float bb = b2[0];
    #pragma unroll
    for (int a = 0; a < 2; ++a) {
      const int m = a * 512 + tid;
      const int row = m >> 4;
      const int g4 = (m & 15) * 4;
      const float4 d = *(const float4*)(sraw + (size_t)(i0 + row) * LL + j0 + g4);
      float4 o;
      float x;
      x = 0.25f * (d.x + B[(g4 + 0) * 65 + row]) + bb; o.x = 1.f / (1.f + expf(-x));
      x = 0.25f * (d.y + B[(g4 + 1) * 65 + row]) + bb; o.y = 1.f / (1.f + expf(-x));
      x = 0.25f * (d.z + B[(g4 + 2) * 65 + row]) + bb; o.z = 1.f / (1.f + expf(-x));
      x = 0.25f * (d.w + B[(g4 + 3) * 65 + row]) + bb; o.w = 1.f / (1.f + expf(-x));
      *(float4*)(out + (size_t)(i0 + row) * LL + j0 + g4) = o;
    }
  }
}

// ---------------------------------------------------------------------------
extern "C" void kernel_launch(void* const* d_in, const int* in_sizes, int n_in,
                              void* d_out, int out_size, void* d_ws, size_t ws_size,
                              hipStream_t stream) {
  const float* S  = (const float*)d_in[0];   // [L, D]
  const float* W1 = (const float*)d_in[1];   // [H, 2D]
  const float* b1 = (const float*)d_in[2];   // [H]
  const float* W2 = (const float*)d_in[3];   // [1, H]
  const float* b2 = (const float*)d_in[4];   // [1]
  float* out = (float*)d_out;
  float* ws  = (float*)d_ws;

  void* kargs[] = {
    (void*)&S, (void*)&W1, (void*)&b1, (void*)&W2, (void*)&b2,
    (void*)&ws, (void*)&out
  };
  hipLaunchCooperativeKernel((const void*)sp_mega, dim3(256), dim3(512),
                             kargs, 0, stream);
}

// Round 10
// 58.498 us; speedup vs baseline: 3.9454x; 3.9454x over previous
//
#include <hip/hip_runtime.h>
#include <math.h>

#define LL 1024
#define DD 512
#define HH 256

// ws layout (floats):
//   pC  : [4][512][1024] @ 0        gemm K-partials (n = mat*256+h)  (8 MB)
//   sraw: [1024][1024]   @ 2097152  P(i,j) = A_i + B_j + sum|t+u|w   (4 MB)

// ---------------------------------------------------------------------------
// Kernel 1 (R7-proven): GEMM partials. C[i][n] = sum_k S[i][k]*W1[n&255][...]
// Tile 128i x 64n x 128k, 512 thr, 4i x 4n per thread. grid (8,8,4)=256.
// 8 b128 per 64 FMAs. Dbuf BK=32.
// ---------------------------------------------------------------------------
__global__ __launch_bounds__(512) void sp_gemm(
    const float* __restrict__ S, const float* __restrict__ W1,
    float* __restrict__ pC) {
  __shared__ float Sl[2][128][36];   // 36.9 KB
  __shared__ float Wl[2][64][36];    // 18.4 KB

  const int tid = threadIdx.x;
  const int tx  = tid & 15;          // n = n0 + tx + 16b
  const int ty  = tid >> 4;          // i = i0 + 4ty + a, ty 0..31
  const int i0  = blockIdx.x * 128;
  const int n0  = blockIdx.y * 64;
  const int kz  = blockIdx.z * 128;

  const int srow = tid >> 3;         // 0..63
  const int ssl  = tid & 7;
  const int wn   = n0 + srow;
  const float* s0 = S + (size_t)(i0 + srow) * DD + kz + 4 * ssl;
  const float* s1 = S + (size_t)(i0 + 64 + srow) * DD + kz + 4 * ssl;
  const float* w0 = W1 + (size_t)(wn & 255) * (2 * DD) + (wn >> 8) * DD + kz + 4 * ssl;

  float4 sA, sB, wA;
  auto ld = [&](int c) {
    sA = *(const float4*)(s0 + 32 * c);
    sB = *(const float4*)(s1 + 32 * c);
    wA = *(const float4*)(w0 + 32 * c);
  };
  auto st = [&](int b) {
    *(float4*)&Sl[b][srow][4 * ssl]      = sA;
    *(float4*)&Sl[b][64 + srow][4 * ssl] = sB;
    *(float4*)&Wl[b][srow][4 * ssl]      = wA;
  };

  float acc[4][4] = {{0.f}};

  ld(0); st(0); __syncthreads();

  for (int c = 0; c < 4; ++c) {
    const int cur = c & 1;
    if (c < 3) ld(c + 1);
    #pragma unroll 2
    for (int k4 = 0; k4 < 8; ++k4) {
      float4 wf[4], sf[4];
      #pragma unroll
      for (int b = 0; b < 4; ++b) wf[b] = *(const float4*)&Wl[cur][tx + 16 * b][4 * k4];
      #pragma unroll
      for (int a = 0; a < 4; ++a) sf[a] = *(const float4*)&Sl[cur][4 * ty + a][4 * k4];
      #pragma unroll
      for (int a = 0; a < 4; ++a) {
        #pragma unroll
        for (int b = 0; b < 4; ++b) {
          acc[a][b] += sf[a].x * wf[b].x + sf[a].y * wf[b].y +
                       sf[a].z * wf[b].z + sf[a].w * wf[b].w;
        }
      }
    }
    if (c < 3) st(cur ^ 1);
    __syncthreads();
  }

  float* base = pC + (size_t)blockIdx.z * (512 * LL);
  #pragma unroll
  for (int b = 0; b < 4; ++b) {
    const int n = n0 + tx + 16 * b;
    *(float4*)(base + (size_t)n * LL + i0 + 4 * ty) =
        make_float4(acc[0][b], acc[1][b], acc[2][b], acc[3][b]);
  }
}

// ---------------------------------------------------------------------------
// Kernel 2: pairwise. P(i,j) = A_i + B_j + sum_h |t_i+u_j|*w2_h
// (relu(x)=(x+|x|)/2; the 0.25 total factor lives in symsig).
// Staging sums the 4 K-partials and folds b1 (reduce kernel eliminated).
// 256 thr, tile 64x64, 4i x 4j per thread: inner = 2 ds_read_b128 per
// 16 cells (T-read 16-lane broadcast, U-read 2-way/free). grid (16,16).
// ---------------------------------------------------------------------------
__global__ __launch_bounds__(256) void sp_pairwise(
    const float* __restrict__ pC, const float* __restrict__ b1,
    const float* __restrict__ W2, float* __restrict__ sraw) {
  __shared__ float Tl[HH][72];
  __shared__ float Ul[HH][72];
  __shared__ float PR[2][128];
  __shared__ float As[64], Bs[64];

  const int tid = threadIdx.x;
  const int tx  = tid & 15;       // j = j0 + 4tx + b
  const int ty  = tid >> 4;       // i = i0 + 4ty + a
  const int i0  = blockIdx.y * 64;
  const int j0  = blockIdx.x * 64;
  const size_t PZ = 512 * (size_t)LL;

  // stage: panel element = sum of 4 K-partials (+ b1 for T)
  #pragma unroll 2
  for (int q = 0; q < 16; ++q) {
    const int m = q * 256 + tid;           // 0..4095
    const int h = m >> 4;
    const int g4 = (m & 15) * 4;
    const float* pt = pC + (size_t)h * LL + i0 + g4;
    const float* pu = pC + (size_t)(HH + h) * LL + j0 + g4;
    const float4 t0 = *(const float4*)(pt);
    const float4 t1 = *(const float4*)(pt + PZ);
    const float4 t2 = *(const float4*)(pt + 2 * PZ);
    const float4 t3 = *(const float4*)(pt + 3 * PZ);
    const float4 u0 = *(const float4*)(pu);
    const float4 u1 = *(const float4*)(pu + PZ);
    const float4 u2 = *(const float4*)(pu + 2 * PZ);
    const float4 u3 = *(const float4*)(pu + 3 * PZ);
    const float bb = b1[h];
    *(float4*)&Tl[h][g4] = make_float4(t0.x + t1.x + t2.x + t3.x + bb,
                                       t0.y + t1.y + t2.y + t3.y + bb,
                                       t0.z + t1.z + t2.z + t3.z + bb,
                                       t0.w + t1.w + t2.w + t3.w + bb);
    *(float4*)&Ul[h][g4] = make_float4(u0.x + u1.x + u2.x + u3.x,
                                       u0.y + u1.y + u2.y + u3.y,
                                       u0.z + u1.z + u2.z + u3.z,
                                       u0.w + u1.w + u2.w + u3.w);
  }
  __syncthreads();

  // rank-1 prologue: A_i = sum_h t*w2, B_j = sum_h u*w2
  {
    const int x = tid & 127, hs = tid >> 7;    // hs 0..1 (128 h each)
    const float* pan = (x < 64) ? &Tl[0][x] : &Ul[0][x - 64];
    float p = 0.f;
    #pragma unroll 8
    for (int n = 0; n < 128; ++n) {
      const int h = hs * 128 + n;
      p = fmaf(pan[h * 72], W2[h], p);
    }
    PR[hs][x] = p;
  }
  __syncthreads();
  if (tid < 128) {
    const float s = PR[0][tid] + PR[1][tid];
    if (tid < 64) As[tid] = s; else Bs[tid - 64] = s;
  }
  __syncthreads();

  float acc[4][4] = {{0.f}};

  #pragma unroll 4
  for (int h = 0; h < HH; ++h) {
    const float4 tv4 = *(const float4*)&Tl[h][4 * ty];
    const float4 uv4 = *(const float4*)&Ul[h][4 * tx];
    const float w = W2[h];
    const float tv[4] = {tv4.x, tv4.y, tv4.z, tv4.w};
    const float uv[4] = {uv4.x, uv4.y, uv4.z, uv4.w};
    #pragma unroll
    for (int a = 0; a < 4; ++a) {
      #pragma unroll
      for (int b = 0; b < 4; ++b) {
        acc[a][b] = fmaf(fabsf(tv[a] + uv[b]), w, acc[a][b]);
      }
    }
  }

  #pragma unroll
  for (int a = 0; a < 4; ++a) {
    const float Ai = As[4 * ty + a];
    float4 v;
    v.x = acc[a][0] + Ai + Bs[4 * tx + 0];
    v.y = acc[a][1] + Ai + Bs[4 * tx + 1];
    v.z = acc[a][2] + Ai + Bs[4 * tx + 2];
    v.w = acc[a][3] + Ai + Bs[4 * tx + 3];
    *(float4*)(sraw + (size_t)(i0 + 4 * ty + a) * LL + j0 + 4 * tx) = v;
  }
}

// ---------------------------------------------------------------------------
// Kernel 3: out = sigmoid(0.25*(P + P^T) + b2). 64x64 tiles, grid (16,16),
// 1024 thr, LDS transpose (proven structure).
// ---------------------------------------------------------------------------
__global__ __launch_bounds__(1024) void sp_symsig(
    const float* __restrict__ sraw, const float* __restrict__ b2,
    float* __restrict__ out) {
  __shared__ float B[64][65];
  const int i0 = blockIdx.y * 64;
  const int j0 = blockIdx.x * 64;
  const int r  = threadIdx.x >> 4;   // 0..63
  const int g  = threadIdx.x & 15;   // 0..15

  const float4 bt = *(const float4*)(sraw + (size_t)(j0 + r) * LL + i0 + 4 * g);
  B[r][4 * g + 0] = bt.x;
  B[r][4 * g + 1] = bt.y;
  B[r][4 * g + 2] = bt.z;
  B[r][4 * g + 3] = bt.w;
  __syncthreads();

  const float4 a = *(const float4*)(sraw + (size_t)(i0 + r) * LL + j0 + 4 * g);
  const float bb = b2[0];
  float4 o;
  float x;
  x = 0.25f * (a.x + B[4 * g + 0][r]) + bb; o.x = 1.f / (1.f + expf(-x));
  x = 0.25f * (a.y + B[4 * g + 1][r]) + bb; o.y = 1.f / (1.f + expf(-x));
  x = 0.25f * (a.z + B[4 * g + 2][r]) + bb; o.z = 1.f / (1.f + expf(-x));
  x = 0.25f * (a.w + B[4 * g + 3][r]) + bb; o.w = 1.f / (1.f + expf(-x));
  *(float4*)(out + (size_t)(i0 + r) * LL + j0 + 4 * g) = o;
}

// ---------------------------------------------------------------------------
extern "C" void kernel_launch(void* const* d_in, const int* in_sizes, int n_in,
                              void* d_out, int out_size, void* d_ws, size_t ws_size,
                              hipStream_t stream) {
  const float* S  = (const float*)d_in[0];   // [L, D]
  const float* W1 = (const float*)d_in[1];   // [H, 2D]
  const float* b1 = (const float*)d_in[2];   // [H]
  const float* W2 = (const float*)d_in[3];   // [1, H]
  const float* b2 = (const float*)d_in[4];   // [1]
  float* out = (float*)d_out;

  float* ws   = (float*)d_ws;
  float* pC   = ws;                      // [4][512][1024]
  float* sraw = ws + 4 * 512 * LL;       // [1024][1024]

  hipLaunchKernelGGL(sp_gemm, dim3(8, 8, 4), dim3(512), 0, stream,
                     S, W1, pC);
  hipLaunchKernelGGL(sp_pairwise, dim3(16, 16), dim3(256), 0, stream,
                     pC, b1, W2, sraw);
  hipLaunchKernelGGL(sp_symsig, dim3(16, 16), dim3(1024), 0, stream,
                     sraw, b2, out);
}

// Round 11
// 48.440 us; speedup vs baseline: 4.7647x; 1.2076x over previous
//
#include <hip/hip_runtime.h>
#include <math.h>

#define LL 1024
#define DD 512
#define HH 256

// ws layout (floats):
//   pC : [4][512][1024] @ 0         gemm K-partials (n = mat*256+h)   (8 MB)
//   pz : [2][1024][1024] @ 2097152  pairwise h-half partials          (8 MB)

// ---------------------------------------------------------------------------
// Kernel 1 (R7/R10-proven): GEMM partials. Tile 128i x 64n x 128k, 512 thr,
// 4i x 4n per thread, grid (8,8,4)=256. 8 b128 per 64 FMAs. Dbuf BK=32.
// ---------------------------------------------------------------------------
__global__ __launch_bounds__(512) void sp_gemm(
    const float* __restrict__ S, const float* __restrict__ W1,
    float* __restrict__ pC) {
  __shared__ float Sl[2][128][36];   // 36.9 KB
  __shared__ float Wl[2][64][36];    // 18.4 KB

  const int tid = threadIdx.x;
  const int tx  = tid & 15;          // n = n0 + tx + 16b
  const int ty  = tid >> 4;          // i = i0 + 4ty + a, ty 0..31
  const int i0  = blockIdx.x * 128;
  const int n0  = blockIdx.y * 64;
  const int kz  = blockIdx.z * 128;

  const int srow = tid >> 3;         // 0..63
  const int ssl  = tid & 7;
  const int wn   = n0 + srow;
  const float* s0 = S + (size_t)(i0 + srow) * DD + kz + 4 * ssl;
  const float* s1 = S + (size_t)(i0 + 64 + srow) * DD + kz + 4 * ssl;
  const float* w0 = W1 + (size_t)(wn & 255) * (2 * DD) + (wn >> 8) * DD + kz + 4 * ssl;

  float4 sA, sB, wA;
  auto ld = [&](int c) {
    sA = *(const float4*)(s0 + 32 * c);
    sB = *(const float4*)(s1 + 32 * c);
    wA = *(const float4*)(w0 + 32 * c);
  };
  auto st = [&](int b) {
    *(float4*)&Sl[b][srow][4 * ssl]      = sA;
    *(float4*)&Sl[b][64 + srow][4 * ssl] = sB;
    *(float4*)&Wl[b][srow][4 * ssl]      = wA;
  };

  float acc[4][4] = {{0.f}};

  ld(0); st(0); __syncthreads();

  for (int c = 0; c < 4; ++c) {
    const int cur = c & 1;
    if (c < 3) ld(c + 1);
    #pragma unroll 2
    for (int k4 = 0; k4 < 8; ++k4) {
      float4 wf[4], sf[4];
      #pragma unroll
      for (int b = 0; b < 4; ++b) wf[b] = *(const float4*)&Wl[cur][tx + 16 * b][4 * k4];
      #pragma unroll
      for (int a = 0; a < 4; ++a) sf[a] = *(const float4*)&Sl[cur][4 * ty + a][4 * k4];
      #pragma unroll
      for (int a = 0; a < 4; ++a) {
        #pragma unroll
        for (int b = 0; b < 4; ++b) {
          acc[a][b] += sf[a].x * wf[b].x + sf[a].y * wf[b].y +
                       sf[a].z * wf[b].z + sf[a].w * wf[b].w;
        }
      }
    }
    if (c < 3) st(cur ^ 1);
    __syncthreads();
  }

  float* base = pC + (size_t)blockIdx.z * (512 * LL);
  #pragma unroll
  for (int b = 0; b < 4; ++b) {
    const int n = n0 + tx + 16 * b;
    *(float4*)(base + (size_t)n * LL + i0 + 4 * ty) =
        make_float4(acc[0][b], acc[1][b], acc[2][b], acc[3][b]);
  }
}

// ---------------------------------------------------------------------------
// Kernel 2: pairwise, h-split 2. Block z covers h in [128z, 128z+128):
//   pz[z](i,j) = A_z(i) + B_z(j) + sum_h |t_i+u_j| * w2_h
// with relu(x)=(x+|x|)/2; the 0.25 total factor lives in symsig.
// 512 thr, tile 64x64, 2i x 4j per thread. LDS 74 KB -> 2 blocks/CU
// = 16 waves/CU = 4 waves/SIMD (R10 was 1/SIMD at VALUBusy 34%).
// Staging sums the 4 gemm K-partials and folds b1 into T.
// ---------------------------------------------------------------------------
__global__ __launch_bounds__(512) void sp_pairwise(
    const float* __restrict__ pC, const float* __restrict__ b1,
    const float* __restrict__ W2, float* __restrict__ pz) {
  __shared__ float Tl[128][72];   // 36.9 KB
  __shared__ float Ul[128][72];   // 36.9 KB
  __shared__ float PR[4][128];
  __shared__ float As[64], Bs[64];

  const int tid = threadIdx.x;
  const int tx  = tid & 15;       // j = j0 + 4tx + b
  const int ty  = tid >> 4;       // i = i0 + 2ty + a, ty 0..31
  const int j0  = blockIdx.x * 64;
  const int i0  = blockIdx.y * 64;
  const int hz  = blockIdx.z * 128;
  const size_t PZ = 512 * (size_t)LL;

  // stage: panel element = sum of 4 K-partials (+ b1 for T)
  #pragma unroll
  for (int q = 0; q < 4; ++q) {
    const int m = q * 512 + tid;           // 0..2047
    const int hh = m >> 4;                 // 0..127
    const int g4 = (m & 15) * 4;
    const int h  = hz + hh;
    const float* pt = pC + (size_t)h * LL + i0 + g4;
    const float* pu = pC + (size_t)(HH + h) * LL + j0 + g4;
    const float4 t0 = *(const float4*)(pt);
    const float4 t1 = *(const float4*)(pt + PZ);
    const float4 t2 = *(const float4*)(pt + 2 * PZ);
    const float4 t3 = *(const float4*)(pt + 3 * PZ);
    const float4 u0 = *(const float4*)(pu);
    const float4 u1 = *(const float4*)(pu + PZ);
    const float4 u2 = *(const float4*)(pu + 2 * PZ);
    const float4 u3 = *(const float4*)(pu + 3 * PZ);
    const float bb = b1[h];
    *(float4*)&Tl[hh][g4] = make_float4(t0.x + t1.x + t2.x + t3.x + bb,
                                        t0.y + t1.y + t2.y + t3.y + bb,
                                        t0.z + t1.z + t2.z + t3.z + bb,
                                        t0.w + t1.w + t2.w + t3.w + bb);
    *(float4*)&Ul[hh][g4] = make_float4(u0.x + u1.x + u2.x + u3.x,
                                        u0.y + u1.y + u2.y + u3.y,
                                        u0.z + u1.z + u2.z + u3.z,
                                        u0.w + u1.w + u2.w + u3.w);
  }
  __syncthreads();

  // rank-1 prologue over this h-half: 128 cols x 4 h-slices of 32
  {
    const int x = tid & 127, hs = tid >> 7;    // hs 0..3
    const float* pan = (x < 64) ? &Tl[0][x] : &Ul[0][x - 64];
    float p = 0.f;
    #pragma unroll 8
    for (int n = 0; n < 32; ++n) {
      const int hh = hs * 32 + n;
      p = fmaf(pan[hh * 72], W2[hz + hh], p);
    }
    PR[hs][x] = p;
  }
  __syncthreads();
  if (tid < 128) {
    const float s = PR[0][tid] + PR[1][tid] + PR[2][tid] + PR[3][tid];
    if (tid < 64) As[tid] = s; else Bs[tid - 64] = s;
  }
  __syncthreads();

  float a0[4] = {0.f, 0.f, 0.f, 0.f};
  float a1[4] = {0.f, 0.f, 0.f, 0.f};

  #pragma unroll 4
  for (int hh = 0; hh < 128; ++hh) {
    const float2 tv = *(const float2*)&Tl[hh][2 * ty];
    const float4 uv = *(const float4*)&Ul[hh][4 * tx];
    const float w = W2[hz + hh];
    a0[0] = fmaf(fabsf(tv.x + uv.x), w, a0[0]);
    a0[1] = fmaf(fabsf(tv.x + uv.y), w, a0[1]);
    a0[2] = fmaf(fabsf(tv.x + uv.z), w, a0[2]);
    a0[3] = fmaf(fabsf(tv.x + uv.w), w, a0[3]);
    a1[0] = fmaf(fabsf(tv.y + uv.x), w, a1[0]);
    a1[1] = fmaf(fabsf(tv.y + uv.y), w, a1[1]);
    a1[2] = fmaf(fabsf(tv.y + uv.z), w, a1[2]);
    a1[3] = fmaf(fabsf(tv.y + uv.w), w, a1[3]);
  }

  const float A0 = As[2 * ty], A1 = As[2 * ty + 1];
  const float B0 = Bs[4 * tx], B1 = Bs[4 * tx + 1];
  const float B2 = Bs[4 * tx + 2], B3 = Bs[4 * tx + 3];
  float* po = pz + (size_t)blockIdx.z * ((size_t)LL * LL)
                 + (size_t)(i0 + 2 * ty) * LL + j0 + 4 * tx;
  *(float4*)po = make_float4(a0[0] + A0 + B0, a0[1] + A0 + B1,
                             a0[2] + A0 + B2, a0[3] + A0 + B3);
  *(float4*)(po + LL) = make_float4(a1[0] + A1 + B0, a1[1] + A1 + B1,
                                    a1[2] + A1 + B2, a1[3] + A1 + B3);
}

// ---------------------------------------------------------------------------
// Kernel 3: out = sigmoid(0.25*(pz0+pz1 + (pz0+pz1)^T) + b2).
// 64x64 tiles, grid (16,16), 1024 thr, LDS transpose (proven structure).
// ---------------------------------------------------------------------------
__global__ __launch_bounds__(1024) void sp_symsig(
    const float* __restrict__ pz, const float* __restrict__ b2,
    float* __restrict__ out) {
  __shared__ float B[64][65];
  const int i0 = blockIdx.y * 64;
  const int j0 = blockIdx.x * 64;
  const int r  = threadIdx.x >> 4;   // 0..63
  const int g  = threadIdx.x & 15;   // 0..15
  const size_t L2 = (size_t)LL * LL;

  const float* pm = pz + (size_t)(j0 + r) * LL + i0 + 4 * g;
  const float4 m0 = *(const float4*)(pm);
  const float4 m1 = *(const float4*)(pm + L2);
  B[r][4 * g + 0] = m0.x + m1.x;
  B[r][4 * g + 1] = m0.y + m1.y;
  B[r][4 * g + 2] = m0.z + m1.z;
  B[r][4 * g + 3] = m0.w + m1.w;
  __syncthreads();

  const float* pd = pz + (size_t)(i0 + r) * LL + j0 + 4 * g;
  const float4 d0 = *(const float4*)(pd);
  const float4 d1 = *(const float4*)(pd + L2);
  const float bb = b2[0];
  float4 o;
  float x;
  x = 0.25f * (d0.x + d1.x + B[4 * g + 0][r]) + bb; o.x = 1.f / (1.f + expf(-x));
  x = 0.25f * (d0.y + d1.y + B[4 * g + 1][r]) + bb; o.y = 1.f / (1.f + expf(-x));
  x = 0.25f * (d0.z + d1.z + B[4 * g + 2][r]) + bb; o.z = 1.f / (1.f + expf(-x));
  x = 0.25f * (d0.w + d1.w + B[4 * g + 3][r]) + bb; o.w = 1.f / (1.f + expf(-x));
  *(float4*)(out + (size_t)(i0 + r) * LL + j0 + 4 * g) = o;
}

// ---------------------------------------------------------------------------
extern "C" void kernel_launch(void* const* d_in, const int* in_sizes, int n_in,
                              void* d_out, int out_size, void* d_ws, size_t ws_size,
                              hipStream_t stream) {
  const float* S  = (const float*)d_in[0];   // [L, D]
  const float* W1 = (const float*)d_in[1];   // [H, 2D]
  const float* b1 = (const float*)d_in[2];   // [H]
  const float* W2 = (const float*)d_in[3];   // [1, H]
  const float* b2 = (const float*)d_in[4];   // [1]
  float* out = (float*)d_out;

  float* ws = (float*)d_ws;
  float* pC = ws;                      // [4][512][1024]
  float* pz = ws + 4 * 512 * LL;       // [2][1024][1024]

  hipLaunchKernelGGL(sp_gemm, dim3(8, 8, 4), dim3(512), 0, stream,
                     S, W1, pC);
  hipLaunchKernelGGL(sp_pairwise, dim3(16, 16, 2), dim3(512), 0, stream,
                     pC, b1, W2, pz);
  hipLaunchKernelGGL(sp_symsig, dim3(16, 16), dim3(1024), 0, stream,
                     pz, b2, out);
}